// Round 6
// baseline (432.035 us; speedup 1.0000x reference)
//
#include <hip/hip_runtime.h>
#include <hip/hip_bf16.h>

#define BB 8
#define NN 128
#define DD 128

typedef __attribute__((ext_vector_type(8))) short bf16x8;
typedef __attribute__((ext_vector_type(4))) float floatx4;

__device__ __forceinline__ unsigned short f2bf(float f) {
    // round-to-nearest-even bf16 (finite inputs only)
    unsigned int bits = __float_as_uint(f);
    unsigned int r = bits + 0x7FFFu + ((bits >> 16) & 1u);
    return (unsigned short)(r >> 16);
}

// ws layout (float units)
#define WS_X0   0         // 131072 f
#define WS_X1   131072    // 131072 f
#define WS_W1T  262144    // 34816 ushorts: w1t[n][d] = W1[n&127][(n>>7)*128+d], stride 136
#define WS_W2B  279552    // 17408 ushorts: w2b[e][d] = W2[e][d], stride 136
#define WS_CNT  288256    // 64 ints

// ---------------- K_init: embed gather + bf16 weight images + barrier counters ----------------
__global__ __launch_bounds__(256) void k_init(const int* __restrict__ tok,
                                              const float* __restrict__ embf,
                                              const float* __restrict__ W1f,
                                              const float* __restrict__ W2f,
                                              float* __restrict__ ws) {
    float* x0 = ws + WS_X0;
    unsigned short* gw1t = (unsigned short*)(ws + WS_W1T);
    unsigned short* gw2b = (unsigned short*)(ws + WS_W2B);
    int* cnt = (int*)(ws + WS_CNT);
    int blk = blockIdx.x, t = threadIdx.x;
    if (blk < 32) {                       // x0 = embed[tok]
        int base = blk * 4096;
#pragma unroll
        for (int it = 0; it < 16; ++it) {
            int idx = base + it * 256 + t;
            int r = idx >> 7, d = idx & 127;
            x0[idx] = embf[tok[r] * DD + d];
        }
    } else if (blk < 41) {                // w1t (256x136): B[n][d] = W1[n&127][(n>>7)*128+d]
        int base = (blk - 32) * 4096;
#pragma unroll
        for (int it = 0; it < 16; ++it) {
            int idx = base + it * 256 + t;
            if (idx < 256 * 136) {
                int e = idx / 136, d = idx - e * 136;
                gw1t[idx] = (d < 128) ? f2bf(W1f[(e & 127) * 256 + (e >> 7) * 128 + d])
                                      : (unsigned short)0;
            }
        }
    } else if (blk < 46) {                // w2b (128x136): W2[e][d]
        int base = (blk - 41) * 4096;
#pragma unroll
        for (int it = 0; it < 16; ++it) {
            int idx = base + it * 256 + t;
            if (idx < 128 * 136) {
                int e = idx / 136, d = idx - e * 136;
                gw2b[idx] = (d < 128) ? f2bf(W2f[e * 128 + d]) : (unsigned short)0;
            }
        }
    } else {
        if (t < 64) cnt[t] = 0;
    }
}

// ---------------- K_main: all 5 rounds + head. 256 blocks x 512 threads, 1 block/CU ----------
__global__ __launch_bounds__(512, 2) void k_main(const float* __restrict__ Af,
                                                 const float* __restrict__ b1f,
                                                 const float* __restrict__ b2f,
                                                 const float* __restrict__ Wo1f,
                                                 const float* __restrict__ bo1f,
                                                 const float* __restrict__ Wo2f,
                                                 float* __restrict__ ws,
                                                 float* __restrict__ outp) {
    __shared__ __align__(16) unsigned short w1t[256 * 136];   // 69632 B (later reused for Wo1 f32)
    __shared__ __align__(16) unsigned short w2b[128 * 136];   // 34816 B
    __shared__ __align__(16) unsigned short xb[128 * 136];    // 34816 B; Xb then Hjb
    __shared__ __align__(16) float red[4][4][128];            // 8192 B (later rs for head)
    __shared__ __align__(16) float zs[4][128];                // 2048 B
    __shared__ float a_s[4][128];                             // 2048 B
    __shared__ __align__(16) float hja_s[4][128];             // 2048 B
    __shared__ float b1s[128], b2s[128];                      // 1024 B   (total ~151 KB)

    float* x0 = ws + WS_X0;
    float* x1 = ws + WS_X1;
    const unsigned short* gw1t = (const unsigned short*)(ws + WS_W1T);
    const unsigned short* gw2b = (const unsigned short*)(ws + WS_W2B);
    int* cnt = (int*)(ws + WS_CNT);

    int blk = blockIdx.x;
    int b = blk >> 5, g = blk & 31, i0 = g * 4;
    int t = threadIdx.x;
    int wave = t >> 6, lane = t & 63;
    int col = lane & 15, quad = lane >> 4;

    // ---- persistent staging (once) ----
    {
        const uint4* s1 = (const uint4*)gw1t; uint4* d1 = (uint4*)w1t;
#pragma unroll
        for (int it = 0; it < 9; ++it) { int idx = it * 512 + t; if (idx < 4352) d1[idx] = s1[idx]; }
        const uint4* s2 = (const uint4*)gw2b; uint4* d2 = (uint4*)w2b;
#pragma unroll
        for (int it = 0; it < 5; ++it) { int idx = it * 512 + t; if (idx < 2176) d2[idx] = s2[idx]; }
    }
    if (t < 128) { b1s[t] = b1f[t]; b2s[t] = b2f[t]; }
    a_s[t >> 7][t & 127] = Af[(b * NN + (t & 127)) * NN + i0 + (t >> 7)];  // A[b, j, i0+ii]

    const int myw = i0 >> 4;   // GEMM1 wave whose m-tile holds rows i0..i0+3
    const int qr  = g & 3;     // quad within that tile

    for (int r = 0; r < 5; ++r) {
        const float* cur = (r & 1) ? x1 : x0;
        float* nxt = (r & 1) ? x0 : x1;
        const float* curb = cur + b * NN * DD;
        // ---- stage Xb (bf16) ----
#pragma unroll
        for (int it = 0; it < 8; ++it) {
            int idx = it * 2048 + t * 4;
            int j = idx >> 7, d = idx & 127;
            float4 v = *reinterpret_cast<const float4*>(curb + j * DD + d);
            ushort4 o;
            o.x = f2bf(v.x); o.y = f2bf(v.y); o.z = f2bf(v.z); o.w = f2bf(v.w);
            *reinterpret_cast<ushort4*>(&xb[j * 136 + d]) = o;
        }
        __syncthreads();

        // ---- GEMM1: proj = Xb @ W1^T (m=j: wave's 16 rows; n=0..255) ----
        bf16x8 af[4];
#pragma unroll
        for (int ks = 0; ks < 4; ++ks)
            af[ks] = *reinterpret_cast<const bf16x8*>(&xb[(wave * 16 + col) * 136 + ks * 32 + quad * 8]);
        floatx4 acc1[16];
#pragma unroll
        for (int nt = 0; nt < 16; ++nt) acc1[nt] = (floatx4){0.f, 0.f, 0.f, 0.f};
#pragma unroll
        for (int nt = 0; nt < 16; ++nt)
#pragma unroll
            for (int ks = 0; ks < 4; ++ks) {
                bf16x8 bfc = *reinterpret_cast<const bf16x8*>(&w1t[(nt * 16 + col) * 136 + ks * 32 + quad * 8]);
                acc1[nt] = __builtin_amdgcn_mfma_f32_16x16x32_bf16(af[ks], bfc, acc1[nt], 0, 0, 0);
            }
        // hja capture (n<128): rows i0..i0+3 live in wave myw / quad qr (C: row=quad*4+reg, col=n)
        if (wave == myw && quad == qr) {
#pragma unroll
            for (int nt = 0; nt < 8; ++nt) {
                int d = nt * 16 + col;
#pragma unroll
                for (int rr = 0; rr < 4; ++rr) hja_s[rr][d] = acc1[nt][rr];
            }
        }
        // Hjb (+b1) bf16 into xb region (own rows only -> no cross-wave WAR on A-reads)
#pragma unroll
        for (int nt = 8; nt < 16; ++nt) {
            int d = (nt - 8) * 16 + col;
#pragma unroll
            for (int rr = 0; rr < 4; ++rr) {
                int j = wave * 16 + quad * 4 + rr;
                xb[j * 136 + d] = f2bf(acc1[nt][rr] + b1s[d]);
            }
        }
        __syncthreads();

        // ---- GEMM2 per owned row i: M = relu(H @ W2^T + b2); msg = sum_j a_j * M ----
        int we = wave & 1, wj = wave >> 1;
        int ebase = we * 64, jbase = wj * 32;
        bf16x8 bw[4][4];
#pragma unroll
        for (int et = 0; et < 4; ++et)
#pragma unroll
            for (int ks = 0; ks < 4; ++ks)
                bw[et][ks] = *reinterpret_cast<const bf16x8*>(&w2b[(ebase + et * 16 + col) * 136 + ks * 32 + quad * 8]);
#pragma unroll
        for (int ii = 0; ii < 4; ++ii) {
            floatx4 acc2[2][4];
#pragma unroll
            for (int jt = 0; jt < 2; ++jt)
#pragma unroll
                for (int et = 0; et < 4; ++et) acc2[jt][et] = (floatx4){0.f, 0.f, 0.f, 0.f};
#pragma unroll
            for (int jt = 0; jt < 2; ++jt)
#pragma unroll
                for (int ks = 0; ks < 4; ++ks) {
                    int k0 = ks * 32 + quad * 8;
                    union { bf16x8 v; unsigned int u[4]; } Rw, Ho;
                    Rw.v = *reinterpret_cast<const bf16x8*>(&xb[(jbase + jt * 16 + col) * 136 + k0]);
                    const float* hb = &hja_s[ii][k0];
#pragma unroll
                    for (int p = 0; p < 4; ++p) {   // H = relu(hja_i + Hjb) formed in-register
                        float f0 = __uint_as_float(Rw.u[p] << 16);
                        float f1 = __uint_as_float(Rw.u[p] & 0xFFFF0000u);
                        f0 = fmaxf(f0 + hb[2 * p], 0.f);
                        f1 = fmaxf(f1 + hb[2 * p + 1], 0.f);
                        Ho.u[p] = (unsigned int)f2bf(f0) | ((unsigned int)f2bf(f1) << 16);
                    }
#pragma unroll
                    for (int et = 0; et < 4; ++et)
                        acc2[jt][et] = __builtin_amdgcn_mfma_f32_16x16x32_bf16(Ho.v, bw[et][ks], acc2[jt][et], 0, 0, 0);
                }
#pragma unroll
            for (int et = 0; et < 4; ++et) {
                int e = ebase + et * 16 + col;
                float be = b2s[e];
                float s = 0.f;
#pragma unroll
                for (int jt = 0; jt < 2; ++jt) {
                    int j0 = jbase + jt * 16 + quad * 4;
#pragma unroll
                    for (int rr = 0; rr < 4; ++rr)
                        s += a_s[ii][j0 + rr] * fmaxf(acc2[jt][et][rr] + be, 0.f);
                }
                s += __shfl_xor(s, 16, 64);
                s += __shfl_xor(s, 32, 64);
                if (quad == 0) red[wj][ii][e] = s;
            }
        }
        __syncthreads();
        // ---- finalize x_nxt = x_cur + msg (own 4 rows, coalesced) ----
        {
            int ii = t >> 7, e = t & 127;
            float msg = red[0][ii][e] + red[1][ii][e] + red[2][ii][e] + red[3][ii][e];
            int row = b * NN + i0 + ii;
            float xv = cur[row * DD + e] + msg;
            nxt[row * DD + e] = xv;
            if (r == 4) zs[ii][e] = xv;
        }
        if (r < 4) {   // per-batch barrier across the 32 co-resident blocks of batch b
            __threadfence();
            __syncthreads();
            if (t == 0) {
                __hip_atomic_fetch_add(&cnt[b * 4 + r], 1, __ATOMIC_ACQ_REL, __HIP_MEMORY_SCOPE_AGENT);
                while (__hip_atomic_load(&cnt[b * 4 + r], __ATOMIC_RELAXED, __HIP_MEMORY_SCOPE_AGENT) < 32)
                    __builtin_amdgcn_s_sleep(2);
            }
            __syncthreads();
            __threadfence();
        } else {
            __syncthreads();
        }
    }

    // ---- head (own 4 rows) ----
    float* wo1s = (float*)w1t;   // 128x136 f32 = 69632 B, exactly the w1t footprint
#pragma unroll
    for (int it = 0; it < 32; ++it) {
        int idx = it * 512 + t;
        int e = idx >> 7, d = idx & 127;
        wo1s[e * 136 + d] = Wo1f[idx];
    }
    __syncthreads();
    {
        int ii = t >> 7, e = t & 127;
        float acc = 0.f;
#pragma unroll
        for (int d4 = 0; d4 < 32; ++d4) {
            float4 w = *reinterpret_cast<const float4*>(&wo1s[e * 136 + d4 * 4]);
            float4 z = *reinterpret_cast<const float4*>(&zs[ii][d4 * 4]);
            acc += w.x * z.x + w.y * z.y + w.z * z.z + w.w * z.w;
        }
        ((float*)red)[ii * 128 + e] = fmaxf(acc + bo1f[e], 0.f);
    }
    __syncthreads();
    if (t < 40) {
        int ii = t / 10, o = t - ii * 10;
        const float* rsrow = (const float*)red + ii * 128;
        float s = 0.f;
#pragma unroll
        for (int e = 0; e < 128; ++e) s += rsrow[e] * Wo2f[o * DD + e];
        int row = b * NN + i0 + ii;
        outp[80 + row * 10 + o] = s;             // x_all (8,128,10)
        if (i0 + ii == 0) outp[b * 10 + o] = s;  // out == x_all[:,0,:]
    }
}

extern "C" void kernel_launch(void* const* d_in, const int* in_sizes, int n_in,
                              void* d_out, int out_size, void* d_ws, size_t ws_size,
                              hipStream_t stream) {
    const int*   tok  = (const int*)d_in[0];
    const float* Af   = (const float*)d_in[1];
    const float* embf = (const float*)d_in[2];
    const float* W1f  = (const float*)d_in[3];
    const float* b1f  = (const float*)d_in[4];
    const float* W2f  = (const float*)d_in[5];
    const float* b2f  = (const float*)d_in[6];
    const float* Wo1f = (const float*)d_in[7];
    const float* bo1f = (const float*)d_in[8];
    const float* Wo2f = (const float*)d_in[9];

    float* ws  = (float*)d_ws;
    float* out = (float*)d_out;

    k_init<<<48, 256, 0, stream>>>(tok, embf, W1f, W2f, ws);
    k_main<<<256, 512, 0, stream>>>(Af, b1f, b2f, Wo1f, bo1f, Wo2f, ws, out);
}

// Round 7
// 168.812 us; speedup vs baseline: 2.5593x; 2.5593x over previous
//
#include <hip/hip_runtime.h>
#include <hip/hip_bf16.h>

#define BB 8
#define NN 128
#define DD 128

typedef __attribute__((ext_vector_type(8))) short bf16x8;
typedef __attribute__((ext_vector_type(4))) float floatx4;

__device__ __forceinline__ unsigned short f2bf(float f) {
    // round-to-nearest-even bf16 (finite inputs only)
    unsigned int bits = __float_as_uint(f);
    unsigned int r = bits + 0x7FFFu + ((bits >> 16) & 1u);
    return (unsigned short)(r >> 16);
}

// ws layout (float units)
#define WS_X0   0         // 131072 f
#define WS_X1   131072    // 131072 f
#define WS_W1T  262144    // 34816 ushorts: w1t[n][d] = W1[n&127][(n>>7)*128+d], stride 136
#define WS_W2B  279552    // 17408 ushorts: w2b[e][d] = W2[e][d], stride 136
#define WS_CNT  288256    // 8 batches x 4 rounds x 32 ints (1 cacheline per counter)

// ---------------- K_init: embed gather + bf16 weight images + barrier counters ----------------
__global__ __launch_bounds__(256) void k_init(const int* __restrict__ tok,
                                              const float* __restrict__ embf,
                                              const float* __restrict__ W1f,
                                              const float* __restrict__ W2f,
                                              float* __restrict__ ws) {
    float* x0 = ws + WS_X0;
    unsigned short* gw1t = (unsigned short*)(ws + WS_W1T);
    unsigned short* gw2b = (unsigned short*)(ws + WS_W2B);
    int* cnt = (int*)(ws + WS_CNT);
    int blk = blockIdx.x, t = threadIdx.x;
    if (blk < 32) {                       // x0 = embed[tok]
        int base = blk * 4096;
#pragma unroll
        for (int it = 0; it < 16; ++it) {
            int idx = base + it * 256 + t;
            int r = idx >> 7, d = idx & 127;
            x0[idx] = embf[tok[r] * DD + d];
        }
    } else if (blk < 41) {                // w1t (256x136): B[n][d] = W1[n&127][(n>>7)*128+d]
        int base = (blk - 32) * 4096;
#pragma unroll
        for (int it = 0; it < 16; ++it) {
            int idx = base + it * 256 + t;
            if (idx < 256 * 136) {
                int e = idx / 136, d = idx - e * 136;
                gw1t[idx] = (d < 128) ? f2bf(W1f[(e & 127) * 256 + (e >> 7) * 128 + d])
                                      : (unsigned short)0;
            }
        }
    } else if (blk < 46) {                // w2b (128x136): W2[e][d]
        int base = (blk - 41) * 4096;
#pragma unroll
        for (int it = 0; it < 16; ++it) {
            int idx = base + it * 256 + t;
            if (idx < 128 * 136) {
                int e = idx / 136, d = idx - e * 136;
                gw2b[idx] = (d < 128) ? f2bf(W2f[e * 128 + d]) : (unsigned short)0;
            }
        }
    } else if (blk == 46) {               // zero barrier counters (8*4*32 ints)
#pragma unroll
        for (int it = 0; it < 4; ++it) cnt[it * 256 + t] = 0;
    }
}

// ---------------- K_main: all 5 rounds + head. 256 blocks x 512 threads, 1 block/CU ----------
__global__ __launch_bounds__(512, 2) void k_main(const float* __restrict__ Af,
                                                 const float* __restrict__ b1f,
                                                 const float* __restrict__ b2f,
                                                 const float* __restrict__ Wo1f,
                                                 const float* __restrict__ bo1f,
                                                 const float* __restrict__ Wo2f,
                                                 float* __restrict__ ws,
                                                 float* __restrict__ outp) {
    __shared__ __align__(16) unsigned short w1t[256 * 136];   // 69632 B (later reused for Wo1 f32)
    __shared__ __align__(16) unsigned short w2b[128 * 136];   // 34816 B
    __shared__ __align__(16) unsigned short xb[128 * 136];    // 34816 B; Xb then Hjb
    __shared__ __align__(16) float red[4][4][128];            // 8192 B (later rs for head)
    __shared__ __align__(16) float zs[4][128];                // 2048 B
    __shared__ float a_s[4][128];                             // 2048 B
    __shared__ __align__(16) float hja_s[4][128];             // 2048 B
    __shared__ float b1s[128], b2s[128];                      // 1024 B   (total ~151 KB)

    float* x0 = ws + WS_X0;
    float* x1 = ws + WS_X1;
    const unsigned short* gw1t = (const unsigned short*)(ws + WS_W1T);
    const unsigned short* gw2b = (const unsigned short*)(ws + WS_W2B);
    int* cnt = (int*)(ws + WS_CNT);

    int blk = blockIdx.x;
    int b = blk >> 5, g = blk & 31, i0 = g * 4;
    int t = threadIdx.x;
    int wave = t >> 6, lane = t & 63;
    int col = lane & 15, quad = lane >> 4;

    // ---- persistent staging (once) ----
    {
        const uint4* s1 = (const uint4*)gw1t; uint4* d1 = (uint4*)w1t;
#pragma unroll
        for (int it = 0; it < 9; ++it) { int idx = it * 512 + t; if (idx < 4352) d1[idx] = s1[idx]; }
        const uint4* s2 = (const uint4*)gw2b; uint4* d2 = (uint4*)w2b;
#pragma unroll
        for (int it = 0; it < 5; ++it) { int idx = it * 512 + t; if (idx < 2176) d2[idx] = s2[idx]; }
    }
    if (t < 128) { b1s[t] = b1f[t]; b2s[t] = b2f[t]; }
    a_s[t >> 7][t & 127] = Af[(b * NN + (t & 127)) * NN + i0 + (t >> 7)];  // A[b, j, i0+ii]

    // this thread's owned x element: row b*NN+i0+(t>>7), col t&127 — carried in-register
    float xown = x0[(b * NN + i0 + (t >> 7)) * DD + (t & 127)];

    const int myw = i0 >> 4;   // GEMM1 wave whose m-tile holds rows i0..i0+3
    const int qr  = g & 3;     // quad within that tile

    for (int r = 0; r < 5; ++r) {
        const float* cur = (r & 1) ? x1 : x0;
        float* nxt = (r & 1) ? x0 : x1;
        const float* curb = cur + b * NN * DD;
        // ---- stage Xb (bf16) via agent-scope (sc0 sc1) loads: coherent, no cache-walk ----
#pragma unroll
        for (int it = 0; it < 16; ++it) {
            int idx = it * 1024 + t * 2;
            int j = idx >> 7, d = idx & 127;
            unsigned long long v = __hip_atomic_load(
                (unsigned long long*)(curb + j * DD + d),
                __ATOMIC_RELAXED, __HIP_MEMORY_SCOPE_AGENT);
            unsigned int lo = (unsigned int)v, hi2 = (unsigned int)(v >> 32);
            unsigned int packed = (unsigned int)f2bf(__uint_as_float(lo))
                                | ((unsigned int)f2bf(__uint_as_float(hi2)) << 16);
            *reinterpret_cast<unsigned int*>(&xb[j * 136 + d]) = packed;
        }
        __syncthreads();

        // ---- GEMM1: proj = Xb @ W1^T (m=j: wave's 16 rows; n=0..255) ----
        bf16x8 af[4];
#pragma unroll
        for (int ks = 0; ks < 4; ++ks)
            af[ks] = *reinterpret_cast<const bf16x8*>(&xb[(wave * 16 + col) * 136 + ks * 32 + quad * 8]);
        floatx4 acc1[16];
#pragma unroll
        for (int nt = 0; nt < 16; ++nt) acc1[nt] = (floatx4){0.f, 0.f, 0.f, 0.f};
#pragma unroll
        for (int nt = 0; nt < 16; ++nt)
#pragma unroll
            for (int ks = 0; ks < 4; ++ks) {
                bf16x8 bfc = *reinterpret_cast<const bf16x8*>(&w1t[(nt * 16 + col) * 136 + ks * 32 + quad * 8]);
                acc1[nt] = __builtin_amdgcn_mfma_f32_16x16x32_bf16(af[ks], bfc, acc1[nt], 0, 0, 0);
            }
        // hja capture (n<128): rows i0..i0+3 live in wave myw / quad qr (C: row=quad*4+reg, col=n)
        if (wave == myw && quad == qr) {
#pragma unroll
            for (int nt = 0; nt < 8; ++nt) {
                int d = nt * 16 + col;
#pragma unroll
                for (int rr = 0; rr < 4; ++rr) hja_s[rr][d] = acc1[nt][rr];
            }
        }
        // Hjb (+b1) bf16 into xb region (own rows only -> no cross-wave WAR on A-reads)
#pragma unroll
        for (int nt = 8; nt < 16; ++nt) {
            int d = (nt - 8) * 16 + col;
#pragma unroll
            for (int rr = 0; rr < 4; ++rr) {
                int j = wave * 16 + quad * 4 + rr;
                xb[j * 136 + d] = f2bf(acc1[nt][rr] + b1s[d]);
            }
        }
        __syncthreads();

        // ---- GEMM2 per owned row i: M = relu(H @ W2^T + b2); msg = sum_j a_j * M ----
        int we = wave & 1, wj = wave >> 1;
        int ebase = we * 64, jbase = wj * 32;
        bf16x8 bw[4][4];
#pragma unroll
        for (int et = 0; et < 4; ++et)
#pragma unroll
            for (int ks = 0; ks < 4; ++ks)
                bw[et][ks] = *reinterpret_cast<const bf16x8*>(&w2b[(ebase + et * 16 + col) * 136 + ks * 32 + quad * 8]);
#pragma unroll
        for (int ii = 0; ii < 4; ++ii) {
            floatx4 acc2[2][4];
#pragma unroll
            for (int jt = 0; jt < 2; ++jt)
#pragma unroll
                for (int et = 0; et < 4; ++et) acc2[jt][et] = (floatx4){0.f, 0.f, 0.f, 0.f};
#pragma unroll
            for (int jt = 0; jt < 2; ++jt)
#pragma unroll
                for (int ks = 0; ks < 4; ++ks) {
                    int k0 = ks * 32 + quad * 8;
                    union { bf16x8 v; unsigned int u[4]; } Rw, Ho;
                    Rw.v = *reinterpret_cast<const bf16x8*>(&xb[(jbase + jt * 16 + col) * 136 + k0]);
                    const float* hb = &hja_s[ii][k0];
#pragma unroll
                    for (int p = 0; p < 4; ++p) {   // H = relu(hja_i + Hjb) formed in-register
                        float f0 = __uint_as_float(Rw.u[p] << 16);
                        float f1 = __uint_as_float(Rw.u[p] & 0xFFFF0000u);
                        f0 = fmaxf(f0 + hb[2 * p], 0.f);
                        f1 = fmaxf(f1 + hb[2 * p + 1], 0.f);
                        Ho.u[p] = (unsigned int)f2bf(f0) | ((unsigned int)f2bf(f1) << 16);
                    }
#pragma unroll
                    for (int et = 0; et < 4; ++et)
                        acc2[jt][et] = __builtin_amdgcn_mfma_f32_16x16x32_bf16(Ho.v, bw[et][ks], acc2[jt][et], 0, 0, 0);
                }
#pragma unroll
            for (int et = 0; et < 4; ++et) {
                int e = ebase + et * 16 + col;
                float be = b2s[e];
                float s = 0.f;
#pragma unroll
                for (int jt = 0; jt < 2; ++jt) {
                    int j0 = jbase + jt * 16 + quad * 4;
#pragma unroll
                    for (int rr = 0; rr < 4; ++rr)
                        s += a_s[ii][j0 + rr] * fmaxf(acc2[jt][et][rr] + be, 0.f);
                }
                s += __shfl_xor(s, 16, 64);
                s += __shfl_xor(s, 32, 64);
                if (quad == 0) red[wj][ii][e] = s;
            }
        }
        __syncthreads();
        // ---- finalize: xown += msg; publish via sc0/sc1 store (write-through, no fence) ----
        {
            int ii = t >> 7, e = t & 127;
            float msg = red[0][ii][e] + red[1][ii][e] + red[2][ii][e] + red[3][ii][e];
            xown += msg;
            if (r < 4) {
                __hip_atomic_store((float*)(nxt + (b * NN + i0 + ii) * DD + e), xown,
                                   __ATOMIC_RELAXED, __HIP_MEMORY_SCOPE_AGENT);
            } else {
                zs[ii][e] = xown;
            }
        }
        if (r < 4) {   // fence-free per-batch barrier (32 co-resident blocks, padded counters)
            __atomic_signal_fence(__ATOMIC_SEQ_CST);
            __builtin_amdgcn_s_waitcnt(0);        // this wave's stores reached coherence point
            __syncthreads();                       // all waves' stores drained
            if (t == 0) {
                int* myc = cnt + (b * 4 + r) * 32; // one cacheline per counter
                __hip_atomic_fetch_add(myc, 1, __ATOMIC_RELAXED, __HIP_MEMORY_SCOPE_AGENT);
                while (__hip_atomic_load(myc, __ATOMIC_RELAXED, __HIP_MEMORY_SCOPE_AGENT) < 32)
                    __builtin_amdgcn_s_sleep(8);
            }
            __syncthreads();
        } else {
            __syncthreads();
        }
    }

    // ---- head (own 4 rows) ----
    float* wo1s = (float*)w1t;   // 128x136 f32 = 69632 B, exactly the w1t footprint
#pragma unroll
    for (int it = 0; it < 32; ++it) {
        int idx = it * 512 + t;
        int e = idx >> 7, d = idx & 127;
        wo1s[e * 136 + d] = Wo1f[idx];
    }
    __syncthreads();
    {
        int ii = t >> 7, e = t & 127;
        float acc = 0.f;
#pragma unroll
        for (int d4 = 0; d4 < 32; ++d4) {
            float4 w = *reinterpret_cast<const float4*>(&wo1s[e * 136 + d4 * 4]);
            float4 z = *reinterpret_cast<const float4*>(&zs[ii][d4 * 4]);
            acc += w.x * z.x + w.y * z.y + w.z * z.z + w.w * z.w;
        }
        ((float*)red)[ii * 128 + e] = fmaxf(acc + bo1f[e], 0.f);
    }
    __syncthreads();
    if (t < 40) {
        int ii = t / 10, o = t - ii * 10;
        const float* rsrow = (const float*)red + ii * 128;
        float s = 0.f;
#pragma unroll
        for (int e = 0; e < 128; ++e) s += rsrow[e] * Wo2f[o * DD + e];
        int row = b * NN + i0 + ii;
        outp[80 + row * 10 + o] = s;             // x_all (8,128,10)
        if (i0 + ii == 0) outp[b * 10 + o] = s;  // out == x_all[:,0,:]
    }
}

extern "C" void kernel_launch(void* const* d_in, const int* in_sizes, int n_in,
                              void* d_out, int out_size, void* d_ws, size_t ws_size,
                              hipStream_t stream) {
    const int*   tok  = (const int*)d_in[0];
    const float* Af   = (const float*)d_in[1];
    const float* embf = (const float*)d_in[2];
    const float* W1f  = (const float*)d_in[3];
    const float* b1f  = (const float*)d_in[4];
    const float* W2f  = (const float*)d_in[5];
    const float* b2f  = (const float*)d_in[6];
    const float* Wo1f = (const float*)d_in[7];
    const float* bo1f = (const float*)d_in[8];
    const float* Wo2f = (const float*)d_in[9];

    float* ws  = (float*)d_ws;
    float* out = (float*)d_out;

    k_init<<<48, 256, 0, stream>>>(tok, embf, W1f, W2f, ws);
    k_main<<<256, 512, 0, stream>>>(Af, b1f, b2f, Wo1f, bo1f, Wo2f, ws, out);
}